// Round 2
// baseline (1020.247 us; speedup 1.0000x reference)
//
#include <hip/hip_runtime.h>
#include <hip/hip_bf16.h>
#include <math.h>

// GAT: N=100000 nodes, E=1600000 edges (+N self loops), 3 layers.
// Input dtype (fp32 vs bf16) detected at runtime on-device (flag in ws).

#define NNODES 100000
#define NEDGES 1600000
#define ENTOT  (NEDGES + NNODES)
#define NEG_SLOPE 0.2f
#define BN_EPS 1e-5f

typedef unsigned short u16;
typedef unsigned int u32;

__device__ __forceinline__ float b2f(u16 u){ union{u32 i; float f;} v; v.i=((u32)u)<<16; return v.f; }
// load external float tensor element i; f=1 -> fp32, f=0 -> bf16
__device__ __forceinline__ float ldf(const void* p, int i, int f){
  return f ? ((const float*)p)[i] : b2f(((const u16*)p)[i]);
}

// ---------------- dtype probe ----------------
// If x is bf16, even-indexed u16s are bf16 randn values: exponent never 0x00/0xFF.
// If x is fp32, even-indexed u16s are low mantissa halves: ~uniform bits.
__global__ void k_detect(const u16* __restrict__ x, int* __restrict__ flag){
  __shared__ int bad;
  if(threadIdx.x==0) bad=0;
  __syncthreads();
  int cnt=0;
  for(int i=threadIdx.x;i<4096;i+=256){
    u16 v = x[2*i];
    int ex = (v>>7)&0xff;
    if(ex==0xff || (ex==0 && (v&0x7fff)!=0)) cnt++;
  }
  atomicAdd(&bad,cnt);
  __syncthreads();
  if(threadIdx.x==0) flag[0] = (bad>4)?1:0;   // 1 = fp32, 0 = bf16
}

// ---------------- CSR build ----------------
__global__ void k_hist(const int* __restrict__ ei, int* __restrict__ cnt){
  int i = blockIdx.x*256 + threadIdx.x;
  if(i>=ENTOT) return;
  int d = (i<NEDGES)? ei[NEDGES+i] : (i-NEDGES);
  atomicAdd(&cnt[d], 1);
}

#define SCAN_M (NNODES+1)
#define SCAN_NB ((SCAN_M + 2047)/2048)

__global__ void k_scan_a(const int* __restrict__ cnt, int* __restrict__ bsum){
  __shared__ int red[256];
  int b=blockIdx.x, t=threadIdx.x;
  int base = b*2048 + t*8;
  int s=0;
  #pragma unroll
  for(int j=0;j<8;j++){ int idx=base+j; s += (idx<NNODES)? cnt[idx]:0; }
  red[t]=s; __syncthreads();
  for(int o=128;o>0;o>>=1){ if(t<o) red[t]+=red[t+o]; __syncthreads(); }
  if(t==0) bsum[b]=red[0];
}

__global__ void k_scan_b(int* bsum){
  if(threadIdx.x==0){
    int run=0;
    for(int i=0;i<SCAN_NB;i++){ int v=bsum[i]; bsum[i]=run; run+=v; }
  }
}

__global__ void k_scan_c(const int* __restrict__ cnt, const int* __restrict__ bsum,
                         int* __restrict__ row_ptr){
  __shared__ int lds[256];
  int b=blockIdx.x, t=threadIdx.x;
  int base=b*2048+t*8;
  int v[8]; int s=0;
  #pragma unroll
  for(int j=0;j<8;j++){ int idx=base+j; int x=(idx<NNODES)?cnt[idx]:0; v[j]=s; s+=x; }
  lds[t]=s; __syncthreads();
  for(int o=1;o<256;o<<=1){
    int other=0; if(t>=o) other=lds[t-o];
    __syncthreads();
    lds[t]+=other;
    __syncthreads();
  }
  int texcl = lds[t] - s;
  int off0 = bsum[b] + texcl;
  #pragma unroll
  for(int j=0;j<8;j++){ int idx=base+j; if(idx<SCAN_M) row_ptr[idx]=off0+v[j]; }
}

__global__ void k_scatter(const int* __restrict__ ei, const int* __restrict__ row_ptr,
                          int* __restrict__ nxt, int* __restrict__ col){
  int i=blockIdx.x*256+threadIdx.x;
  if(i>=ENTOT) return;
  int s,d;
  if(i<NEDGES){ s=ei[i]; d=ei[NEDGES+i]; } else { s=d=i-NEDGES; }
  int pos = row_ptr[d] + atomicAdd(&nxt[d],1);
  col[pos]=s;
}

// ---------------- GEMM + attention-coefficient epilogue ----------------
// h[row][col] = sum_k X[row][k]*W[k][col]; fused alpha_src/dst head dots.
// W staged in LDS as [k/4][col][4] so each lane reads a contiguous 16B frag.
template<int K, int OUTC, int HIDC, bool XEXT>
__global__ __launch_bounds__(256) void k_gemm_alpha(
    const void* __restrict__ xin, const void* __restrict__ W,
    const void* __restrict__ avs, const void* __restrict__ avd,
    float* __restrict__ hout, float* __restrict__ asrc, float* __restrict__ adst,
    const int* __restrict__ flagp)
{
  const int f = flagp[0];
  __shared__ __align__(16) float wt[K*OUTC];
  __shared__ float hrow[4][OUTC];
  int t=threadIdx.x;
  for(int idx=t; idx<K*OUTC; idx+=256){
    int kq = idx/(4*OUTC); int rem = idx - kq*4*OUTC; int col=rem>>2; int j=rem&3;
    wt[idx] = ldf(W, (4*kq+j)*OUTC + col, f);
  }
  __syncthreads();
  int wave=t>>6, lane=t&63;
  int row0 = blockIdx.x*64 + wave*16;
  for(int ri=0; ri<16; ri++){
    int row = row0+ri;
    bool valid = row < NNODES;
    float acc=0.f, acc2=0.f;
    if(valid){
      if(XEXT && f==0){
        // bf16 external input
        const uint4* xr = (const uint4*)((const u16*)xin + (size_t)row*K);
        #pragma unroll 4
        for(int k8=0;k8<K/8;k8++){
          uint4 xq = xr[k8];   // wave-uniform broadcast load of 8 bf16
          float x0=b2f(xq.x&0xffff), x1=b2f(xq.x>>16);
          float x2=b2f(xq.y&0xffff), x3=b2f(xq.y>>16);
          float x4=b2f(xq.z&0xffff), x5=b2f(xq.z>>16);
          float x6=b2f(xq.w&0xffff), x7=b2f(xq.w>>16);
          float4 wv  = *(const float4*)&wt[((2*k8  )*OUTC + lane)*4];
          float4 wv2 = *(const float4*)&wt[((2*k8+1)*OUTC + lane)*4];
          acc += x0*wv.x + x1*wv.y + x2*wv.z + x3*wv.w;
          acc += x4*wv2.x + x5*wv2.y + x6*wv2.z + x7*wv2.w;
        }
      } else {
        // fp32 input (external-fp32 or internal buffer)
        const float4* xr = (const float4*)((const float*)xin + (size_t)row*K);
        #pragma unroll 4
        for(int kq=0;kq<K/4;kq++){
          float4 xv = xr[kq];  // wave-uniform broadcast
          float4 wv = *(const float4*)&wt[(kq*OUTC + lane)*4];
          acc += xv.x*wv.x + xv.y*wv.y + xv.z*wv.z + xv.w*wv.w;
          if(OUTC==80 && lane<16){
            float4 w2v = *(const float4*)&wt[(kq*OUTC + 64+lane)*4];
            acc2 += xv.x*w2v.x + xv.y*w2v.y + xv.z*w2v.z + xv.w*w2v.w;
          }
        }
      }
    }
    hrow[wave][lane]=acc;
    if(OUTC==80 && lane<16) hrow[wave][64+lane]=acc2;
    __syncthreads();
    // alpha dots: 4 tasks (src/dst x head), 16 lanes each
    int grp=lane>>4, cc=lane&15, head=grp&1;
    const void* av = (grp<2)? avs : avd;
    float part=0.f;
    for(int c=cc;c<HIDC;c+=16) part += hrow[wave][head*HIDC+c]*ldf(av,head*HIDC+c,f);
    #pragma unroll
    for(int o=1;o<16;o<<=1) part += __shfl_xor(part,o,64);
    if(valid && cc==0){
      float* dst = (grp<2)? asrc : adst;
      dst[row*2+head]=part;
    }
    if(valid){
      hout[(size_t)row*OUTC + lane]=acc;
      if(OUTC==80 && lane<16) hout[(size_t)row*OUTC+64+lane]=acc2;
    }
    __syncthreads();
  }
}

// ---------------- per-destination softmax + aggregation ----------------
// one wave per dst node; lane = channel; edges broadcast via shuffles.
template<int OUTC, bool FINAL>
__global__ __launch_bounds__(256) void k_agg(
  const int* __restrict__ row_ptr, const int* __restrict__ col,
  const float* __restrict__ hin, const float* __restrict__ asrc, const float* __restrict__ adst,
  const void* __restrict__ bias, float* __restrict__ hout, void* __restrict__ outv,
  const int* __restrict__ flagp)
{
  const int f = flagp[0];
  int wave = threadIdx.x>>6, lane=threadIdx.x&63;
  int d = blockIdx.x*4 + wave;
  if(d>=NNODES) return;
  int base=row_ptr[d], deg=row_ptr[d+1]-base;
  float ad0=adst[2*d], ad1=adst[2*d+1];
  // pass 1: per-head max over incoming edges (lane-parallel)
  float m0=-INFINITY, m1=-INFINITY;
  for(int off=0; off<deg; off+=64){
    int j=off+lane;
    if(j<deg){
      int cs=col[base+j];
      float t0=asrc[2*cs]+ad0;   t0 = t0>0.f? t0 : NEG_SLOPE*t0;
      float t1=asrc[2*cs+1]+ad1; t1 = t1>0.f? t1 : NEG_SLOPE*t1;
      m0=fmaxf(m0,t0); m1=fmaxf(m1,t1);
    }
  }
  #pragma unroll
  for(int o=1;o<64;o<<=1){ m0=fmaxf(m0,__shfl_xor(m0,o,64)); m1=fmaxf(m1,__shfl_xor(m1,o,64)); }
  // pass 2: exp-sum + weighted accumulate (edges broadcast, channels across lanes)
  float s0=0.f,s1=0.f, acc=0.f, acc2=0.f;
  const int headA = (OUTC==80) ? (lane<40?0:1) : (lane>>5);
  for(int off=0; off<deg; off+=64){
    int j=off+lane;
    bool v = j<deg;
    int cs = v? col[base+j] : 0;
    float e0=-INFINITY, e1=-INFINITY;
    if(v){
      float t0=asrc[2*cs]+ad0;   e0 = t0>0.f? t0 : NEG_SLOPE*t0;
      float t1=asrc[2*cs+1]+ad1; e1 = t1>0.f? t1 : NEG_SLOPE*t1;
    }
    int nv = deg-off; if(nv>64) nv=64;
    int n4=(nv+3)>>2;
    for(int g=0; g<n4; g++){
      #pragma unroll
      for(int u=0;u<4;u++){
        int tt=4*g+u;
        int   ss  = __shfl(cs, tt&63, 64);
        float pe0 = __shfl(e0, tt&63, 64);
        float pe1 = __shfl(e1, tt&63, 64);
        float p0 = __expf(pe0-m0);   // -inf lanes -> 0
        float p1 = __expf(pe1-m1);
        s0+=p0; s1+=p1;
        float pm = headA? p1:p0;
        acc += pm * hin[(size_t)ss*OUTC + lane];
        if(OUTC==80 && lane<16) acc2 += p1 * hin[(size_t)ss*OUTC + 64 + lane];
      }
    }
  }
  float inv0 = s0>0.f ? 1.0f/s0 : 0.f;
  float inv1 = s1>0.f ? 1.0f/s1 : 0.f;
  if(!FINAL){
    float val = acc*(headA?inv1:inv0) + ldf(bias,lane,f);
    hout[(size_t)d*OUTC + lane] = val;
  } else {
    // lanes 0..63 hold channels 0..63; lanes 0..15 slot-B hold channels 64..79 (head1)
    float valA = acc*(headA?inv1:inv0);
    float valB = acc2*inv1;
    int co=lane;
    float oA = __shfl(valA, (40+co)&63, 64);  // head1 out-ch co (co<24)
    float oB = __shfl(valB, (co+40)&63, 64);  // head1 out-ch co (co>=24)
    if(co<40){
      float h1v = (co<24)? oA : oB;
      float res = 0.5f*(valA + h1v) + ldf(bias,co,f);
      if(f) ((float*)outv)[(size_t)d*40+co] = res;
      else  ((__hip_bfloat16*)outv)[(size_t)d*40+co] = __float2bfloat16(res);
    }
  }
}

// ---------------- batch norm ----------------
__global__ __launch_bounds__(256) void k_bnstats(const float* __restrict__ h, float* __restrict__ stats){
  __shared__ float red[4][128];
  int t=threadIdx.x; int c=t&63; int g=t>>6;
  float s=0.f,q=0.f;
  for(int r=blockIdx.x*4+g; r<NNODES; r+=gridDim.x*4){
    float v=h[(size_t)r*64+c]; s+=v; q+=v*v;
  }
  red[g][c]=s; red[g][64+c]=q;
  __syncthreads();
  if(t<128){
    float tot=red[0][t]+red[1][t]+red[2][t]+red[3][t];
    atomicAdd(&stats[t], tot);
  }
}

__global__ __launch_bounds__(256) void k_bnapply(float* __restrict__ h, const float* __restrict__ stats,
                          const void* __restrict__ gm, const void* __restrict__ bt,
                          const int* __restrict__ flagp){
  const int f = flagp[0];
  int i=blockIdx.x*256+threadIdx.x;
  if(i>=NNODES*64) return;
  int c=i&63;
  float mu=stats[c]*(1.0f/NNODES);
  float var=stats[64+c]*(1.0f/NNODES)-mu*mu;
  var = var>0.f?var:0.f;
  float y = ldf(gm,c,f)*(h[i]-mu)*rsqrtf(var+BN_EPS)+ldf(bt,c,f);
  h[i] = y>0.f? y : __expf(y)-1.0f;   // ELU(alpha=1)
}

extern "C" void kernel_launch(void* const* d_in, const int* in_sizes, int n_in,
                              void* d_out, int out_size, void* d_ws, size_t ws_size,
                              hipStream_t stream){
  const void* x  =d_in[0];
  const int* ei =(const int*)d_in[1];
  const void* W0 =d_in[2];  const void* as0=d_in[3];  const void* ad0=d_in[4];
  const void* b0 =d_in[5];  const void* g0 =d_in[6];  const void* bt0=d_in[7];
  const void* W1 =d_in[8];  const void* as1=d_in[9];  const void* ad1=d_in[10];
  const void* b1 =d_in[11]; const void* g1 =d_in[12]; const void* bt1=d_in[13];
  const void* W2 =d_in[14]; const void* as2=d_in[15]; const void* ad2=d_in[16];
  const void* b2 =d_in[17];

  char* ws=(char*)d_ws;
  size_t off=0;
  auto alloc=[&](size_t bytes)->void*{ void* p=ws+off; off+=(bytes+255)&~(size_t)255; return p; };
  int*   flag   =(int*)  alloc(256);
  int*   row_ptr=(int*)  alloc((size_t)(NNODES+1)*4);
  int*   cnt    =(int*)  alloc((size_t)NNODES*4);
  int*   colx   =(int*)  alloc((size_t)ENTOT*4);
  int*   bsum   =(int*)  alloc((size_t)SCAN_NB*4);
  float* hA     =(float*)alloc((size_t)NNODES*80*4);  // also aliased as h2 (80ch) in layer 2
  float* hB     =(float*)alloc((size_t)NNODES*64*4);
  float* asrc   =(float*)alloc((size_t)NNODES*2*4);
  float* adst   =(float*)alloc((size_t)NNODES*2*4);
  float* stats  =(float*)alloc(128*4);
  float* h2     = hA;

  k_detect<<<1,256,0,stream>>>((const u16*)x, flag);

  // CSR by destination (shared by all 3 layers)
  hipMemsetAsync(cnt,0,(size_t)NNODES*4,stream);
  int gE=(ENTOT+255)/256;
  k_hist   <<<gE,256,0,stream>>>(ei,cnt);
  k_scan_a <<<SCAN_NB,256,0,stream>>>(cnt,bsum);
  k_scan_b <<<1,64,0,stream>>>(bsum);
  k_scan_c <<<SCAN_NB,256,0,stream>>>(cnt,bsum,row_ptr);
  hipMemsetAsync(cnt,0,(size_t)NNODES*4,stream);
  k_scatter<<<gE,256,0,stream>>>(ei,row_ptr,cnt,colx);

  int gG=(NNODES+63)/64;
  int gA=(NNODES+3)/4;
  // layer 0: x(128) -> hA(64); agg -> hB; BN+ELU in place
  k_gemm_alpha<128,64,32,true ><<<gG,256,0,stream>>>(x ,W0,as0,ad0,hA,asrc,adst,flag);
  k_agg<64,false><<<gA,256,0,stream>>>(row_ptr,colx,hA,asrc,adst,b0,hB,nullptr,flag);
  hipMemsetAsync(stats,0,512,stream);
  k_bnstats<<<256,256,0,stream>>>(hB,stats);
  k_bnapply<<<(NNODES*64+255)/256,256,0,stream>>>(hB,stats,g0,bt0,flag);
  // layer 1: hB -> hA; agg -> hB; BN+ELU
  k_gemm_alpha<64,64,32,false><<<gG,256,0,stream>>>(hB,W1,as1,ad1,hA,asrc,adst,flag);
  k_agg<64,false><<<gA,256,0,stream>>>(row_ptr,colx,hA,asrc,adst,b1,hB,nullptr,flag);
  hipMemsetAsync(stats,0,512,stream);
  k_bnstats<<<256,256,0,stream>>>(hB,stats);
  k_bnapply<<<(NNODES*64+255)/256,256,0,stream>>>(hB,stats,g1,bt1,flag);
  // layer 2: hB -> h2(80); agg (head mean) -> d_out
  k_gemm_alpha<64,80,40,false><<<gG,256,0,stream>>>(hB,W2,as2,ad2,h2,asrc,adst,flag);
  k_agg<80,true ><<<gA,256,0,stream>>>(row_ptr,colx,h2,asrc,adst,b2,nullptr,d_out,flag);

  (void)in_sizes;(void)n_in;(void)out_size;(void)ws_size;
}